// Round 1
// baseline (51.332 us; speedup 1.0000x reference)
//
#include <hip/hip_runtime.h>

#define OUTP 7
#define CCH  512
#define HF   50
#define WF   50
#define NROI 256

__global__ __launch_bounds__(256) void roipool_kernel(
    const float* __restrict__ x,
    const float* __restrict__ rois,
    float* __restrict__ out,
    int total)
{
    const int stride = gridDim.x * blockDim.x;
    for (int idx = blockIdx.x * blockDim.x + threadIdx.x; idx < total; idx += stride) {
        int n   = idx / (CCH * OUTP * OUTP);
        int rem = idx - n * (CCH * OUTP * OUTP);
        int c   = rem / (OUTP * OUTP);
        int pp  = rem - c * (OUTP * OUTP);
        int ph  = pp / OUTP;
        int pw  = pp - ph * OUTP;

        // scale = 50/800 = 0.0625 exactly; (int) truncation == jnp astype(int32)
        const float* r = rois + n * 4;
        int rx = (int)(r[0] * 0.0625f);
        int ry = (int)(r[1] * 0.0625f);
        int rw = (int)(r[2] * 0.0625f);
        int rh = (int)(r[3] * 0.0625f);
        int sh = rh + 1, sw = rw + 1;

        int ys = ry + (ph * sh) / OUTP;
        int ye = ry + ((ph + 1) * sh + OUTP - 1) / OUTP;
        int xs = rx + (pw * sw) / OUTP;
        int xe = rx + ((pw + 1) * sw + OUTP - 1) / OUTP;
        // For these input ranges ye<=47<H and xe<=47<W, so no clamping needed;
        // every bin is nonempty (sh,sw >= 6) so m is never left at -inf.

        const float* f = x + c * (HF * WF);
        float m = -INFINITY;
        for (int y = ys; y < ye; ++y) {
            const float* row = f + y * WF;
            for (int xx = xs; xx < xe; ++xx)
                m = fmaxf(m, row[xx]);
        }
        out[idx] = m;
    }
}

extern "C" void kernel_launch(void* const* d_in, const int* in_sizes, int n_in,
                              void* d_out, int out_size, void* d_ws, size_t ws_size,
                              hipStream_t stream) {
    const float* x    = (const float*)d_in[0];   // (1, 512, 50, 50)
    // d_in[1] is img — only its shape matters (hardcoded scale 0.0625)
    const float* rois = (const float*)d_in[2];   // (256, 4)
    float* out = (float*)d_out;                  // (256, 512, 7, 7) fp32

    const int total = NROI * CCH * OUTP * OUTP;  // 6,422,528
    const int block = 256;
    int grid = (total + block - 1) / block;
    if (grid > 2048) grid = 2048;
    roipool_kernel<<<grid, block, 0, stream>>>(x, rois, out, total);
}